// Round 3
// baseline (167.358 us; speedup 1.0000x reference)
//
#include <hip/hip_runtime.h>

// TimeVaryingDelayLine forward — LDS multi-pass gather.
//
// R2 analysis: bound by vector-memory address transactions (64 random lines
// per wave gather, ~3cyc each), not HBM or L2 bytes. Fix: stage the tap
// window in LDS chunks and resolve the random reads in LDS banking.
//
// Block = 256 threads x 32 elems = 8192 contiguous t of one series.
// Window = [t0, t0+48192) in xpad coords (xpad = concat(buffer, x)).
// 3 passes x 16384 floats (64KB LDS). Per element we keep
// (tap1 byte addr rel. window, frac, acc) in registers, fully unrolled.
// Pass p covers rel bytes [p*64KB, (p+1)*64KB); common case both taps in
// pass, rare chunk-straddle handled by edge branches.

#define MAX_DELAY 40000
#define T_LEN     1000000
#define XPAD      (MAX_DELAY + T_LEN)   // 1,040,000 floats per series
#define CHUNK     8192                  // output elems per block
#define S_ELEMS   16384                 // LDS floats per pass
#define S_BYTES   (S_ELEMS * 4)         // 65536
#define NPASS     3                     // ceil((MAX_DELAY+CHUNK)/S_ELEMS)
#define CPS       123                   // chunks per series = ceil(T_LEN/CHUNK)
#define NXCD      8

__global__ __launch_bounds__(256) void tvdl_kernel(
    const float* __restrict__ x,
    const float* __restrict__ dt,
    const float* __restrict__ buf,
    float* __restrict__ y,
    int chunk_per_xcd)
{
    __shared__ float lds[S_ELEMS];

    // XCD-contiguous remap: grid = 1968 = 8 * 246, bijective.
    int bid = blockIdx.x;
    int lb  = (bid & (NXCD - 1)) * chunk_per_xcd + (bid >> 3);
    int nc  = lb / CPS;                 // series 0..15
    int c   = lb - nc * CPS;            // chunk 0..122
    int t0  = c * CHUNK;
    int tid = threadIdx.x;

    const float* __restrict__ xs  = x   + (size_t)nc * T_LEN;
    const float* __restrict__ bs  = buf + (size_t)nc * MAX_DELAY;
    const float* __restrict__ dts = dt  + (size_t)nc * T_LEN;
    float*       __restrict__ ys  = y   + (size_t)nc * T_LEN;

    // ---------------- per-element setup ----------------
    // thread owns 8 groups of 4 consecutive elements; group k starts at
    // local offset (k*256+tid)*4.
    int   b1[8][4];     // byte addr of tap1 relative to window start t0
    float fr[8][4];
    float acc[8][4];
    int   gvalid[8];

#pragma unroll
    for (int k = 0; k < 8; ++k) {
        int go   = (k * 256 + tid) * 4;          // local elem offset of group
        int lidx = t0 + go;                      // global t of group start
        gvalid[k] = (lidx < T_LEN);
        int lc = lidx; if (lc > T_LEN - 4) lc = T_LEN - 4;   // clamp for tail
        float4 d4 = *reinterpret_cast<const float4*>(dts + lc);
        float dv[4] = {d4.x, d4.y, d4.z, d4.w};
#pragma unroll
        for (int j = 0; j < 4; ++j) {
            float dvj = dv[j];
            int   i0  = (int)dvj;                // dt >= 0 -> trunc == floor
            fr[k][j]  = dvj - (float)i0;
            // tap0 xpad idx = MAX_DELAY + t0 + le - i0 ; tap1 = that - 1.
            // relative to window start t0: (MAX_DELAY - 1 + le - i0)
            b1[k][j]  = (MAX_DELAY - 1 + (go + j) - i0) * 4;
            acc[k][j] = 0.0f;
        }
    }

    // ---------------- staging helpers (inlined) ----------------
    float4 sreg[16];

    // prologue: stage pass 0
#pragma unroll
    for (int q = 0; q < 16; ++q) {
        int g = t0 + (q * 256 + tid) * 4;        // pass 0 region
        if (g > XPAD - 4) g = XPAD - 4;
        const float* src = (g >= MAX_DELAY) ? (xs + (g - MAX_DELAY)) : (bs + g);
        sreg[q] = *reinterpret_cast<const float4*>(src);
    }
#pragma unroll
    for (int q = 0; q < 16; ++q)
        *reinterpret_cast<float4*>(&lds[(q * 256 + tid) * 4]) = sreg[q];
    __syncthreads();

    // ---------------- pass loop ----------------
#pragma unroll
    for (int p = 0; p < NPASS; ++p) {
        // issue global loads for pass p+1 (overlap with compute below)
        if (p + 1 < NPASS) {
#pragma unroll
            for (int q = 0; q < 16; ++q) {
                int g = t0 + (p + 1) * S_ELEMS + (q * 256 + tid) * 4;
                if (g > XPAD - 4) g = XPAD - 4;
                const float* src = (g >= MAX_DELAY) ? (xs + (g - MAX_DELAY))
                                                    : (bs + g);
                sreg[q] = *reinterpret_cast<const float4*>(src);
            }
        }

        // compute pass p
#pragma unroll
        for (int k = 0; k < 8; ++k) {
#pragma unroll
            for (int j = 0; j < 4; ++j) {
                int bb = b1[k][j] - p * S_BYTES;
                unsigned ub = (unsigned)bb;
                if (ub < (unsigned)(S_BYTES - 4)) {
                    // both taps in this chunk: tap1 at ub, tap0 at ub+4
                    float t1  = *reinterpret_cast<const float*>(
                                    reinterpret_cast<const char*>(lds) + ub);
                    float t0v = *reinterpret_cast<const float*>(
                                    reinterpret_cast<const char*>(lds) + ub + 4);
                    float f = fr[k][j];
                    acc[k][j] = fmaf(1.0f - f, t0v, fmaf(f, t1, acc[k][j]));
                } else if (ub == (unsigned)(S_BYTES - 4)) {
                    // tap1 is last slot; tap0 belongs to next pass
                    acc[k][j] = fmaf(fr[k][j], lds[S_ELEMS - 1], acc[k][j]);
                } else if (bb == -4) {
                    // tap0 is slot 0; tap1 belonged to previous pass
                    acc[k][j] = fmaf(1.0f - fr[k][j], lds[0], acc[k][j]);
                }
            }
        }

        __syncthreads();                          // all waves done reading lds
        if (p + 1 < NPASS) {
#pragma unroll
            for (int q = 0; q < 16; ++q)
                *reinterpret_cast<float4*>(&lds[(q * 256 + tid) * 4]) = sreg[q];
            __syncthreads();                      // next chunk visible
        }
    }

    // ---------------- store ----------------
#pragma unroll
    for (int k = 0; k < 8; ++k) {
        if (gvalid[k]) {
            int go = (k * 256 + tid) * 4;
            *reinterpret_cast<float4*>(ys + t0 + go) =
                make_float4(acc[k][0], acc[k][1], acc[k][2], acc[k][3]);
        }
    }
}

extern "C" void kernel_launch(void* const* d_in, const int* in_sizes, int n_in,
                              void* d_out, int out_size, void* d_ws, size_t ws_size,
                              hipStream_t stream) {
    const float* x   = (const float*)d_in[0];
    const float* dt  = (const float*)d_in[1];
    const float* buf = (const float*)d_in[2];
    float* y = (float*)d_out;

    int nseries = out_size / T_LEN;                 // 16
    int blocks  = nseries * CPS;                    // 1968 = 8 * 246
    int chunk_per_xcd = blocks / NXCD;              // 246
    tvdl_kernel<<<blocks, 256, 0, stream>>>(x, dt, buf, y, chunk_per_xcd);
}

// Round 4
// 82.185 us; speedup vs baseline: 2.0364x; 2.0364x over previous
//
#include <hip/hip_runtime.h>
#include <stdint.h>

// TimeVaryingDelayLine forward — LDS multi-pass gather, v2 (spill-free).
//
// R3 failed on VGPR spills (WRITE_SIZE 435MB of scratch). Fixes:
//  - __launch_bounds__(256,2): LDS already caps at 2 blocks/CU, so allow the
//    allocator the full 256-VGPR/wave budget -> b1/fr/acc (96 regs) stay in RF.
//  - Stage via __builtin_amdgcn_global_load_lds width=16 (no sreg round-trip,
//    no ds_write): LDS dest is the required linear wave-uniform+lane*16 layout,
//    global src per-lane (region select + clamp).
//
// Block = 256 threads x 32 elems = 8192 contiguous t of one series.
// Window = xpad[t0, t0+48192), staged in 3 passes x 16384 floats (64KB LDS).

#define MAX_DELAY 40000
#define T_LEN     1000000
#define XPAD      (MAX_DELAY + T_LEN)   // 1,040,000 floats per series
#define CHUNK     8192
#define S_ELEMS   16384
#define S_BYTES   (S_ELEMS * 4)
#define NPASS     3
#define CPS       123                   // ceil(T_LEN/CHUNK)
#define NXCD      8

typedef __attribute__((address_space(3))) uint32_t       lds_u32;
typedef const __attribute__((address_space(1))) uint32_t glb_u32;

__global__ __launch_bounds__(256, 2) void tvdl_kernel(
    const float* __restrict__ x,
    const float* __restrict__ dt,
    const float* __restrict__ buf,
    float* __restrict__ y,
    int chunk_per_xcd)
{
    __shared__ float lds[S_ELEMS];

    int bid = blockIdx.x;
    int lb  = (bid & (NXCD - 1)) * chunk_per_xcd + (bid >> 3);  // XCD-contiguous
    int nc  = lb / CPS;                 // series 0..15
    int c   = lb - nc * CPS;            // chunk 0..122
    int t0  = c * CHUNK;
    int tid = threadIdx.x;

    const float* __restrict__ xs  = x   + (size_t)nc * T_LEN;
    const float* __restrict__ bs  = buf + (size_t)nc * MAX_DELAY;
    const float* __restrict__ dts = dt  + (size_t)nc * T_LEN;
    float*       __restrict__ ys  = y   + (size_t)nc * T_LEN;

    // ---- per-element setup (dt read ONCE; state held in registers) ----
    int   b1[8][4];     // byte offset of tap1 relative to window start
    float fr[8][4];
    float acc[8][4];

#pragma unroll
    for (int k = 0; k < 8; ++k) {
        int go   = (k * 256 + tid) * 4;
        int lidx = t0 + go;
        int lc   = lidx > T_LEN - 4 ? T_LEN - 4 : lidx;   // tail-chunk clamp
        float4 d4 = *reinterpret_cast<const float4*>(dts + lc);
        float dv[4] = {d4.x, d4.y, d4.z, d4.w};
#pragma unroll
        for (int j = 0; j < 4; ++j) {
            float dvj = dv[j];
            int   i0  = (int)dvj;                 // dt >= 0 -> trunc == floor
            fr[k][j]  = dvj - (float)i0;
            b1[k][j]  = (MAX_DELAY - 1 + (go + j) - i0) * 4;
            acc[k][j] = 0.0f;
        }
    }

    // ---- pass loop ----
#pragma unroll
    for (int p = 0; p < NPASS; ++p) {
        // stage xpad[t0 + p*S_ELEMS ...) into lds via direct-to-LDS DMA
#pragma unroll
        for (int q = 0; q < 16; ++q) {
            int g = t0 + p * S_ELEMS + (q * 256 + tid) * 4;
            if (g > XPAD - 4) g = XPAD - 4;       // tail clamp (dup loads, harmless)
            const float* src = (g >= MAX_DELAY) ? (xs + (g - MAX_DELAY))
                                                : (bs + g);
            // LDS dest: wave-uniform base; HW adds lane*16
            float* dst = lds + (size_t)(q * 256 + (tid & 192)) * 4;
            __builtin_amdgcn_global_load_lds((glb_u32*)src, (lds_u32*)dst, 16, 0, 0);
        }
        __syncthreads();   // compiler drains vmcnt before barrier

        // compute pass p
#pragma unroll
        for (int k = 0; k < 8; ++k) {
#pragma unroll
            for (int j = 0; j < 4; ++j) {
                int      bb = b1[k][j] - p * S_BYTES;
                unsigned ub = (unsigned)bb;
                if (ub < (unsigned)(S_BYTES - 4)) {
                    // both taps resident: tap1 at ub, tap0 at ub+4 (ds_read2_b32)
                    const float* lp = (const float*)((const char*)lds + ub);
                    float t1v = lp[0];
                    float t0v = lp[1];
                    float f   = fr[k][j];
                    acc[k][j] = fmaf(1.0f - f, t0v, fmaf(f, t1v, acc[k][j]));
                } else if (ub == (unsigned)(S_BYTES - 4)) {
                    // tap1 is last slot; tap0 arrives next pass
                    acc[k][j] = fmaf(fr[k][j], lds[S_ELEMS - 1], acc[k][j]);
                } else if (bb == -4) {
                    // tap0 is slot 0; tap1 was last slot of previous pass
                    acc[k][j] = fmaf(1.0f - fr[k][j], lds[0], acc[k][j]);
                }
            }
        }

        if (p + 1 < NPASS) __syncthreads();   // all reads done before overwrite
    }

    // ---- store ----
#pragma unroll
    for (int k = 0; k < 8; ++k) {
        int go = (k * 256 + tid) * 4;
        if (t0 + go < T_LEN) {
            *reinterpret_cast<float4*>(ys + t0 + go) =
                make_float4(acc[k][0], acc[k][1], acc[k][2], acc[k][3]);
        }
    }
}

extern "C" void kernel_launch(void* const* d_in, const int* in_sizes, int n_in,
                              void* d_out, int out_size, void* d_ws, size_t ws_size,
                              hipStream_t stream) {
    const float* x   = (const float*)d_in[0];
    const float* dt  = (const float*)d_in[1];
    const float* buf = (const float*)d_in[2];
    float* y = (float*)d_out;

    int nseries = out_size / T_LEN;                 // 16
    int blocks  = nseries * CPS;                    // 1968 = 8 * 246
    int chunk_per_xcd = blocks / NXCD;              // 246
    tvdl_kernel<<<blocks, 256, 0, stream>>>(x, dt, buf, y, chunk_per_xcd);
}